// Round 6
// baseline (1869.959 us; speedup 1.0000x reference)
//
#include <hip/hip_runtime.h>

// SSGC: h = alpha*x0 + (1-alpha)/K * sum_{k=1..K} (D^-1/2 A_hat D^-1/2)^k x0 ; out = h W^T + b
// N=50000, E=1.6M, D=128, K=16, alpha=0.05.
// R13: slice-resident gather at MLP 16. R12 proved slice-major + slice-dispatch gives
//      ~88% L2 hit on gathers but halved per-lane MLP (8) and doubled agg time; the
//      R9..R12 series shows duration ~ 1/MLP. This round keeps R12's residency
//      mechanism and restores 16 gathers-in-flight via NODE-PAIR waves: one wave
//      owns nodes (2p,2p+1) whose CSR ranges are contiguous (expected 64 edges);
//      records loaded 128/batch (two nt dwordx2), 4 edges per gather instr, so a
//      full batch = 16 independent gathers per lane. Boundary handled branch-free
//      (w0 = e<bpos ? w : 0; w1 = w-w0) accumulating both nodes. Butterfly fold;
//      grp0 writes node0, grp1 writes node1. Dynamic 25000-block grid.
//      deg kept as R9 (hard plateau ~24G scattered atomics/s across 3 schedules).

#define N_NODES 50000
#define N_EDGES 1600000
#define D 128
#define K_HOPS 16
#define ALPHA 0.05f
#define HCOEF ((1.0f - ALPHA) / (float)K_HOPS)
#define NREP 8
#define N_SBLK ((N_NODES + 255) / 256)   // 196 scan blocks

// deg: 8 edges/thread -> replica of edge i is ((i >> 11) & 7) (2048 edges per block).
#define DEG_IPT 8
#define REP_OF(i) (((i) >> 11) & (NREP - 1))

// agg: 4 feature slices of 16 dwords (32 bf16 feats, 64B) per node; node-pair waves.
#define N_SLICES 4
#define SLICE_STRIDE ((size_t)N_NODES * 16)    // dwords per slice
#define N_PAIRS (N_NODES / 2)                  // 25000
#define PAIR_BLOCKS (N_PAIRS / 4)              // 6250 blocks per slice (4 pairs/block)

__device__ __forceinline__ unsigned int f2bf(float f) {
    unsigned int u = __float_as_uint(f);
    return (u + 0x7FFFu + ((u >> 16) & 1u)) >> 16;   // RNE
}
__device__ __forceinline__ unsigned int pack_bf2(float x, float y) {
    return f2bf(x) | (f2bf(y) << 16);
}
__device__ __forceinline__ float bf_lo(unsigned int w) { return __uint_as_float(w << 16); }
__device__ __forceinline__ float bf_hi(unsigned int w) { return __uint_as_float(w & 0xFFFF0000u); }

// Replicated in-degree histogram, 8 edges per thread (two int4 loads).
__global__ void deg_kernel(const int* __restrict__ dst, int* __restrict__ degR,
                           int* __restrict__ rank, int e) {
    int gid = blockIdx.x * 256 + threadIdx.x;
    int i0 = gid * DEG_IPT;
    if (i0 >= e) return;
    int rep = REP_OF(i0);                    // all 8 edges share one replica
    int* base = degR + rep * N_NODES;
    int4 d0 = *(const int4*)&dst[i0];
    int4 d1 = *(const int4*)&dst[i0 + 4];
    int r[8];
    r[0] = atomicAdd(&base[d0.x], 1);
    r[1] = atomicAdd(&base[d0.y], 1);
    r[2] = atomicAdd(&base[d0.z], 1);
    r[3] = atomicAdd(&base[d0.w], 1);
    r[4] = atomicAdd(&base[d1.x], 1);
    r[5] = atomicAdd(&base[d1.y], 1);
    r[6] = atomicAdd(&base[d1.z], 1);
    r[7] = atomicAdd(&base[d1.w], 1);
    *(int4*)&rank[i0]     = make_int4(r[0], r[1], r[2], r[3]);
    *(int4*)&rank[i0 + 4] = make_int4(r[4], r[5], r[6], r[7]);
}

// Fold replicas: degR[r][i] becomes the exclusive prefix over replicas (pref),
// deg[i] = total. Also computes dinv/selfw.
__global__ void combine_kernel(int* __restrict__ degR, int* __restrict__ deg,
                               float* __restrict__ dinv, float* __restrict__ selfw, int n) {
    int i = blockIdx.x * 256 + threadIdx.x;
    if (i < n) {
        int run = 0;
        #pragma unroll
        for (int r = 0; r < NREP; ++r) {
            int v = degR[r * N_NODES + i];
            degR[r * N_NODES + i] = run;   // in-place: degR becomes pref
            run += v;
        }
        deg[i] = run;
        float di = rsqrtf((float)(run + 1));
        dinv[i] = di;
        selfw[i] = di * di;
    }
}

// 256-thread block exclusive scan (shfl wave scans + 4-wave LDS combine).
__device__ __forceinline__ int block_scan_excl(int v) {
    __shared__ int ws[4];
    int tid = threadIdx.x, lane = tid & 63, wid = tid >> 6;
    int s = v;
    #pragma unroll
    for (int off = 1; off < 64; off <<= 1) {
        int t = __shfl_up(s, off, 64);
        if (lane >= off) s += t;
    }
    if (lane == 63) ws[wid] = s;
    __syncthreads();
    int woff = 0;
    #pragma unroll
    for (int w = 0; w < 3; ++w)
        if (w < wid) woff += ws[w];
    return woff + s - v;
}

__global__ void scan_part(const int* __restrict__ deg, int* __restrict__ part, int n) {
    int i = blockIdx.x * 256 + threadIdx.x;
    int v = (i < n) ? deg[i] : 0;
    #pragma unroll
    for (int off = 1; off < 64; off <<= 1) v += __shfl_xor(v, off, 64);
    __shared__ int ws[4];
    if ((threadIdx.x & 63) == 0) ws[threadIdx.x >> 6] = v;
    __syncthreads();
    if (threadIdx.x == 0) part[blockIdx.x] = ws[0] + ws[1] + ws[2] + ws[3];
}

__global__ void scan_mid(int* __restrict__ part, int nb) {
    int tid = threadIdx.x;
    int v = (tid < nb) ? part[tid] : 0;
    int e = block_scan_excl(v);
    if (tid < nb) part[tid] = e;
}

__global__ void scan_fin(const int* __restrict__ deg, const int* __restrict__ part,
                         int* __restrict__ row_start, int n) {
    int i = blockIdx.x * 256 + threadIdx.x;
    int v = (i < n) ? deg[i] : 0;
    int e = block_scan_excl(v) + part[blockIdx.x];
    if (i < n) row_start[i] = e;
    if (i == n - 1) row_start[n] = e + v;
}

// One 8B scattered store per edge: record = (src, bitcast(norm weight)).
// 4 edges/thread for MLP on the random 4B gathers.
__global__ void scatter_kernel(const int* __restrict__ src, const int* __restrict__ dst,
                               const int* __restrict__ rank, const int* __restrict__ row_start,
                               const int* __restrict__ pref, int2* __restrict__ csr,
                               const float* __restrict__ dinv, int e) {
    int gid = blockIdx.x * 256 + threadIdx.x;
    int i0 = gid * 4;
    if (i0 >= e) return;
    int4 dv = *(const int4*)&dst[i0];
    int4 sv = *(const int4*)&src[i0];
    int4 rv = *(const int4*)&rank[i0];
    int d[4] = {dv.x, dv.y, dv.z, dv.w};
    int s[4] = {sv.x, sv.y, sv.z, sv.w};
    int r[4] = {rv.x, rv.y, rv.z, rv.w};
    int pos[4];
    float w[4];
    #pragma unroll
    for (int q = 0; q < 4; ++q) {
        int rep = REP_OF(i0 + q);
        pos[q] = row_start[d[q]] + pref[rep * N_NODES + d[q]] + r[q];
        w[q] = dinv[d[q]] * dinv[s[q]];
    }
    #pragma unroll
    for (int q = 0; q < 4; ++q)
        csr[pos[q]] = make_int2(s[q], __float_as_int(w[q]));
}

// x0 -> packed bf16 x in SLICE-MAJOR layout; h = alpha * x0 (exact f32, node-major).
__global__ void init_kernel(const float2* __restrict__ x0, unsigned int* __restrict__ xbs,
                            float2* __restrict__ h, int n2) {
    int i = blockIdx.x * blockDim.x + threadIdx.x;
    if (i < n2) {
        float2 v = x0[i];
        int node = i >> 6, d = i & 63;
        int slice = d >> 4, sub = d & 15;
        xbs[(size_t)slice * SLICE_STRIDE + (size_t)node * 16 + sub] = pack_bf2(v.x, v.y);
        h[i] = make_float2(ALPHA * v.x, ALPHA * v.y);
    }
}

// W 4-edge steps from record regs (RS,RW). Global edge index e = 4*(t+q)+grp;
// shfl source is e&63 (phase A: records 0..63, phase B: 64..127). Validity and
// the node0/node1 split are branch-free: wq zeroed past cnt; w0 = e<bpos ? wq : 0;
// w1 = wq - w0 (exact). Both accumulators updated every edge (2 extra FMA/edge).
#define PSTEP(W, RS, RW)                                                        \
    {                                                                           \
        unsigned int gv[W];                                                     \
        float wv[W];                                                            \
        _Pragma("unroll") for (int q = 0; q < (W); ++q) {                       \
            int e = 4 * (t + q) + grp;                                          \
            int ss = __shfl((RS), e & 63);                                      \
            wv[q] = __int_as_float(__shfl((RW), e & 63));                       \
            gv[q] = xs[(size_t)ss * 16 + sub];                                  \
        }                                                                       \
        _Pragma("unroll") for (int q = 0; q < (W); ++q) {                       \
            int e = 4 * (t + q) + grp;                                          \
            float wq = (e < cnt) ? wv[q] : 0.f;                                 \
            float w0 = (e < bpos) ? wq : 0.f;                                   \
            float w1 = wq - w0;                                                 \
            float lo = bf_lo(gv[q]), hi = bf_hi(gv[q]);                         \
            acc0x += w0 * lo; acc0y += w0 * hi;                                 \
            acc1x += w1 * lo; acc1y += w1 * hi;                                 \
        }                                                                       \
        t += (W);                                                               \
    }

// Slice-resident aggregation at MLP 16. Wave owns the node pair (2p, 2p+1):
// contiguous CSR range [row_start[2p], row_start[2p+2]), expected 64 edges ->
// one 128-record batch, nf ~ 16 4-edge steps, 16 gathers in flight per lane.
// slice = blockIdx / PAIR_BLOCKS: dispatch order phase-separates slices
// (running window ~1 slice = 3.2MB -> per-XCD L2 resident; 88% hit in R12).
// CSR nt-loaded (streamed); yb/h nt-stored to protect the resident slice.
__global__ __launch_bounds__(256) void agg_kernel(
    const unsigned int* __restrict__ xbs, unsigned int* __restrict__ ybs,
    float2* __restrict__ h2, const float* __restrict__ selfw,
    const int* __restrict__ row_start, const int2* __restrict__ csr, int update_h) {
    int wid = threadIdx.x >> 6;
    int lane = threadIdx.x & 63;
    int grp = lane >> 4, sub = lane & 15;
    int bid = blockIdx.x;
    int slice = bid / PAIR_BLOCKS;
    int pr = (bid % PAIR_BLOCKS) * 4 + wid;    // pair index 0..24999
    int n0 = pr * 2;

    const unsigned int* xs = xbs + (size_t)slice * SLICE_STRIDE;
    int r0 = row_start[n0];
    int rm = row_start[n0 + 1];
    int r1 = row_start[n0 + 2];
    int L = r1 - r0;

    float acc0x = 0.f, acc0y = 0.f, acc1x = 0.f, acc1y = 0.f;

    for (int base = 0; base < L; base += 128) {
        int cnt = L - base;
        if (cnt > 128) cnt = 128;
        int i1 = r0 + base + lane;
        if (i1 >= r1) i1 = r1 - 1;             // clamped records only used with w=0
        int i2 = r0 + base + 64 + lane;
        if (i2 >= r1) i2 = r1 - 1;
        long long rrA = __builtin_nontemporal_load((const long long*)&csr[i1]);
        long long rrB = __builtin_nontemporal_load((const long long*)&csr[i2]);
        int rsA = (int)rrA, rwA = (int)(rrA >> 32);
        int rsB = (int)rrB, rwB = (int)(rrB >> 32);
        int bpos = rm - (r0 + base);           // node0/node1 boundary in this batch
        int nf = (cnt + 3) >> 2;               // ceil 4-edge steps (<=32)
        int tA = nf < 16 ? nf : 16;
        int t = 0;
        // phase A: records 0..63
        if (t + 16 <= tA) PSTEP(16, rsA, rwA);
        if (t + 8 <= tA) PSTEP(8, rsA, rwA);
        if (t + 4 <= tA) PSTEP(4, rsA, rwA);
        while (t < tA) PSTEP(1, rsA, rwA);
        // phase B: records 64..127 (only when cnt > 64)
        if (t + 16 <= nf) PSTEP(16, rsB, rwB);
        if (t + 8 <= nf) PSTEP(8, rsB, rwB);
        if (t + 4 <= nf) PSTEP(4, rsB, rwB);
        while (t < nf) PSTEP(1, rsB, rwB);
    }

    // fold the 4 groups; afterwards every lane holds the totals
    acc0x += __shfl_xor(acc0x, 16, 64); acc0x += __shfl_xor(acc0x, 32, 64);
    acc0y += __shfl_xor(acc0y, 16, 64); acc0y += __shfl_xor(acc0y, 32, 64);
    acc1x += __shfl_xor(acc1x, 16, 64); acc1x += __shfl_xor(acc1x, 32, 64);
    acc1y += __shfl_xor(acc1y, 16, 64); acc1y += __shfl_xor(acc1y, 32, 64);

    if (grp < 2) {                             // grp0 -> node0, grp1 -> node1
        int node = n0 + grp;
        float ax = grp ? acc1x : acc0x;
        float ay = grp ? acc1y : acc0y;
        unsigned int vw = xs[(size_t)node * 16 + sub];   // self row (resident slice)
        float sw = selfw[node];
        float xl = bf_lo(vw), xh = bf_hi(vw);
        ax += sw * xl;
        ay += sw * xh;
        size_t so = (size_t)slice * SLICE_STRIDE + (size_t)node * 16 + sub;
        __builtin_nontemporal_store(pack_bf2(ax, ay), &ybs[so]);
        if (update_h) {
            size_t ho = (size_t)node * 64 + slice * 16 + sub;
            union { long long ll; float2 f; } hu;
            hu.ll = __builtin_nontemporal_load((const long long*)&h2[ho]);
            hu.f.x += HCOEF * (xl + ax);       // x_k (rounded) + x_{k+1} (pre-round)
            hu.f.y += HCOEF * (xh + ay);
            __builtin_nontemporal_store(hu.ll, (long long*)&h2[ho]);
        }
    }
}

// out[r][c] = sum_k h[r][k]*W[c][k] + bias[c]. h and out are DIFFERENT buffers.
// Block: 64 rows x 64 cols, 256 threads, 4x4 acc/thread. k-major LDS tiles.
__global__ __launch_bounds__(256) void gemm_kernel(
    const float* __restrict__ h, const float* __restrict__ w,
    const float* __restrict__ bias, float* __restrict__ out) {
    __shared__ float sAT[128][64];   // [k][row]
    __shared__ float sBT[128][64];   // [k][col]
    int tid = threadIdx.x;
    int row0 = blockIdx.x * 64;
    int col0 = blockIdx.y * 64;

    for (int idx = tid; idx < 64 * 32; idx += 256) {
        int r = idx & 63, kq = idx >> 6;
        float4 v;
        if (row0 + r < N_NODES)
            v = *(const float4*)&h[(size_t)(row0 + r) * D + kq * 4];
        else
            v = make_float4(0.f, 0.f, 0.f, 0.f);
        sAT[kq * 4 + 0][r] = v.x;
        sAT[kq * 4 + 1][r] = v.y;
        sAT[kq * 4 + 2][r] = v.z;
        sAT[kq * 4 + 3][r] = v.w;
    }
    for (int idx = tid; idx < 64 * 32; idx += 256) {
        int c = idx & 63, kq = idx >> 6;
        float4 v = *(const float4*)&w[(size_t)(col0 + c) * D + kq * 4];
        sBT[kq * 4 + 0][c] = v.x;
        sBT[kq * 4 + 1][c] = v.y;
        sBT[kq * 4 + 2][c] = v.z;
        sBT[kq * 4 + 3][c] = v.w;
    }
    __syncthreads();

    int cg = tid & 15;    // cols cg*4..+4
    int rg = tid >> 4;    // rows rg*4..+4
    float acc[4][4] = {};
    #pragma unroll 2
    for (int k = 0; k < 128; ++k) {
        float4 a = *(const float4*)&sAT[k][rg * 4];
        float4 b = *(const float4*)&sBT[k][cg * 4];
        acc[0][0] += a.x * b.x; acc[0][1] += a.x * b.y; acc[0][2] += a.x * b.z; acc[0][3] += a.x * b.w;
        acc[1][0] += a.y * b.x; acc[1][1] += a.y * b.y; acc[1][2] += a.y * b.z; acc[1][3] += a.y * b.w;
        acc[2][0] += a.z * b.x; acc[2][1] += a.z * b.y; acc[2][2] += a.z * b.z; acc[2][3] += a.z * b.w;
        acc[3][0] += a.w * b.x; acc[3][1] += a.w * b.y; acc[3][2] += a.w * b.z; acc[3][3] += a.w * b.w;
    }

    float4 bv = *(const float4*)&bias[col0 + cg * 4];
    #pragma unroll
    for (int i = 0; i < 4; ++i) {
        int r = row0 + rg * 4 + i;
        if (r < N_NODES) {
            float4 ov = make_float4(acc[i][0] + bv.x, acc[i][1] + bv.y,
                                    acc[i][2] + bv.z, acc[i][3] + bv.w);
            *(float4*)&out[(size_t)r * D + col0 + cg * 4] = ov;
        }
    }
}

extern "C" void kernel_launch(void* const* d_in, const int* in_sizes, int n_in,
                              void* d_out, int out_size, void* d_ws, size_t ws_size,
                              hipStream_t stream) {
    const float* node_emb = (const float*)d_in[0];
    const int*   edge     = (const int*)d_in[1];   // [2,E]: row 0 = src, row 1 = dst
    const float* weight   = (const float*)d_in[2]; // [D_OUT, D_IN] row-major
    const float* bias     = (const float*)d_in[3];
    float* out = (float*)d_out;

    char* ws = (char*)d_ws;
    float*        hbuf = (float*)ws;        ws += (size_t)N_NODES * D * sizeof(float);
    unsigned int* xb0  = (unsigned int*)ws; ws += (size_t)N_NODES * 64 * sizeof(unsigned int);
    unsigned int* xb1  = (unsigned int*)ws; ws += (size_t)N_NODES * 64 * sizeof(unsigned int);
    int2*  csr      = (int2*)ws;  ws += (size_t)N_EDGES * sizeof(int2);
    int*   rank     = (int*)ws;   ws += (size_t)N_EDGES * sizeof(int);
    int*   degR     = (int*)ws;   ws += (size_t)NREP * N_NODES * sizeof(int);  // -> pref
    int*   deg      = (int*)ws;   ws += (size_t)N_NODES * sizeof(int);
    int*   row_start= (int*)ws;   ws += (size_t)(N_NODES + 16) * sizeof(int);
    float* dinv     = (float*)ws; ws += (size_t)N_NODES * sizeof(float);
    float* selfw    = (float*)ws; ws += (size_t)N_NODES * sizeof(float);
    int*   part     = (int*)ws;   ws += 256 * sizeof(int);

    const int* srcp = edge;
    const int* dstp = edge + N_EDGES;

    hipMemsetAsync(degR, 0, (size_t)NREP * N_NODES * sizeof(int), stream);

    int deg_threads = N_EDGES / DEG_IPT;                       // 200000, exact
    deg_kernel<<<(deg_threads + 255) / 256, 256, 0, stream>>>(dstp, degR, rank, N_EDGES);
    combine_kernel<<<(N_NODES + 255) / 256, 256, 0, stream>>>(degR, deg, dinv, selfw, N_NODES);
    scan_part<<<N_SBLK, 256, 0, stream>>>(deg, part, N_NODES);
    scan_mid<<<1, 256, 0, stream>>>(part, N_SBLK);
    scan_fin<<<N_SBLK, 256, 0, stream>>>(deg, part, row_start, N_NODES);
    int sc_threads = N_EDGES / 4;                              // 400000, exact
    scatter_kernel<<<(sc_threads + 255) / 256, 256, 0, stream>>>(srcp, dstp, rank, row_start,
                                                                 degR, csr, dinv, N_EDGES);

    int n2 = N_NODES * D / 2;
    init_kernel<<<(n2 + 255) / 256, 256, 0, stream>>>((const float2*)node_emb, xb0,
                                                      (float2*)hbuf, n2);

    unsigned int* cur = xb0;
    unsigned int* nxt = xb1;
    for (int k = 0; k < K_HOPS; ++k) {
        agg_kernel<<<N_SLICES * PAIR_BLOCKS, 256, 0, stream>>>(
            cur, nxt, (float2*)hbuf, selfw, row_start, csr, k & 1);
        unsigned int* tmp = cur; cur = nxt; nxt = tmp;
    }

    // Out-of-place GEMM: reads hbuf (f32), writes d_out.
    dim3 ggrid((N_NODES + 63) / 64, 2);
    gemm_kernel<<<ggrid, 256, 0, stream>>>(hbuf, weight, bias, out);
}

// Round 7
// 1060.659 us; speedup vs baseline: 1.7630x; 1.7630x over previous
//
#include <hip/hip_runtime.h>

// SSGC: h = alpha*x0 + (1-alpha)/K * sum_{k=1..K} (D^-1/2 A_hat D^-1/2)^k x0 ; out = h W^T + b
// N=50000, E=1.6M, D=128, K=16, alpha=0.05.
// R14: revert to the R9 champion (wave-per-node, 64-record coalesced batches,
//      shfl broadcast, stepped 16/8/4 gathers, dynamic 12500-block grid) —
//      every slice/pair/persistent restructure (R10-R13) lost 1.5-2x because
//      R9's per-edge cost (2 shfl + 1 load + 2 FMA) is near-minimal and slicing
//      multiplies it 4x. Micro-opts only:
//      (1) 32-bit gather offsets (xb spans 12.8MB) -> drops 64-bit addr adds
//          per gather instruction;
//      (2) nontemporal CSR loads and nt yb/h stores: the 12.8MB/hop CSR and
//          output streams no longer evict the gather-resident xb lines in L2.
//      deg kept as R9 (hard plateau ~24G scattered atomics/s across 3 schedules).

#define N_NODES 50000
#define N_EDGES 1600000
#define D 128
#define K_HOPS 16
#define ALPHA 0.05f
#define HCOEF ((1.0f - ALPHA) / (float)K_HOPS)
#define NREP 8
#define N_SBLK ((N_NODES + 255) / 256)   // 196 scan blocks

// deg: 8 edges/thread -> replica of edge i is ((i >> 11) & 7) (2048 edges per block).
#define DEG_IPT 8
#define REP_OF(i) (((i) >> 11) & (NREP - 1))

__device__ __forceinline__ unsigned int f2bf(float f) {
    unsigned int u = __float_as_uint(f);
    return (u + 0x7FFFu + ((u >> 16) & 1u)) >> 16;   // RNE
}
__device__ __forceinline__ unsigned int pack_bf2(float x, float y) {
    return f2bf(x) | (f2bf(y) << 16);
}
__device__ __forceinline__ float bf_lo(unsigned int w) { return __uint_as_float(w << 16); }
__device__ __forceinline__ float bf_hi(unsigned int w) { return __uint_as_float(w & 0xFFFF0000u); }

// Replicated in-degree histogram, 8 edges per thread (two int4 loads).
__global__ void deg_kernel(const int* __restrict__ dst, int* __restrict__ degR,
                           int* __restrict__ rank, int e) {
    int gid = blockIdx.x * 256 + threadIdx.x;
    int i0 = gid * DEG_IPT;
    if (i0 >= e) return;
    int rep = REP_OF(i0);                    // all 8 edges share one replica
    int* base = degR + rep * N_NODES;
    int4 d0 = *(const int4*)&dst[i0];
    int4 d1 = *(const int4*)&dst[i0 + 4];
    int r[8];
    r[0] = atomicAdd(&base[d0.x], 1);
    r[1] = atomicAdd(&base[d0.y], 1);
    r[2] = atomicAdd(&base[d0.z], 1);
    r[3] = atomicAdd(&base[d0.w], 1);
    r[4] = atomicAdd(&base[d1.x], 1);
    r[5] = atomicAdd(&base[d1.y], 1);
    r[6] = atomicAdd(&base[d1.z], 1);
    r[7] = atomicAdd(&base[d1.w], 1);
    *(int4*)&rank[i0]     = make_int4(r[0], r[1], r[2], r[3]);
    *(int4*)&rank[i0 + 4] = make_int4(r[4], r[5], r[6], r[7]);
}

// Fold replicas: degR[r][i] becomes the exclusive prefix over replicas (pref),
// deg[i] = total. Also computes dinv/selfw.
__global__ void combine_kernel(int* __restrict__ degR, int* __restrict__ deg,
                               float* __restrict__ dinv, float* __restrict__ selfw, int n) {
    int i = blockIdx.x * 256 + threadIdx.x;
    if (i < n) {
        int run = 0;
        #pragma unroll
        for (int r = 0; r < NREP; ++r) {
            int v = degR[r * N_NODES + i];
            degR[r * N_NODES + i] = run;   // in-place: degR becomes pref
            run += v;
        }
        deg[i] = run;
        float di = rsqrtf((float)(run + 1));
        dinv[i] = di;
        selfw[i] = di * di;
    }
}

// 256-thread block exclusive scan (shfl wave scans + 4-wave LDS combine).
__device__ __forceinline__ int block_scan_excl(int v) {
    __shared__ int ws[4];
    int tid = threadIdx.x, lane = tid & 63, wid = tid >> 6;
    int s = v;
    #pragma unroll
    for (int off = 1; off < 64; off <<= 1) {
        int t = __shfl_up(s, off, 64);
        if (lane >= off) s += t;
    }
    if (lane == 63) ws[wid] = s;
    __syncthreads();
    int woff = 0;
    #pragma unroll
    for (int w = 0; w < 3; ++w)
        if (w < wid) woff += ws[w];
    return woff + s - v;
}

__global__ void scan_part(const int* __restrict__ deg, int* __restrict__ part, int n) {
    int i = blockIdx.x * 256 + threadIdx.x;
    int v = (i < n) ? deg[i] : 0;
    #pragma unroll
    for (int off = 1; off < 64; off <<= 1) v += __shfl_xor(v, off, 64);
    __shared__ int ws[4];
    if ((threadIdx.x & 63) == 0) ws[threadIdx.x >> 6] = v;
    __syncthreads();
    if (threadIdx.x == 0) part[blockIdx.x] = ws[0] + ws[1] + ws[2] + ws[3];
}

__global__ void scan_mid(int* __restrict__ part, int nb) {
    int tid = threadIdx.x;
    int v = (tid < nb) ? part[tid] : 0;
    int e = block_scan_excl(v);
    if (tid < nb) part[tid] = e;
}

__global__ void scan_fin(const int* __restrict__ deg, const int* __restrict__ part,
                         int* __restrict__ row_start, int n) {
    int i = blockIdx.x * 256 + threadIdx.x;
    int v = (i < n) ? deg[i] : 0;
    int e = block_scan_excl(v) + part[blockIdx.x];
    if (i < n) row_start[i] = e;
    if (i == n - 1) row_start[n] = e + v;
}

// One 8B scattered store per edge: record = (src, bitcast(norm weight)).
// 4 edges/thread for MLP on the random 4B gathers.
__global__ void scatter_kernel(const int* __restrict__ src, const int* __restrict__ dst,
                               const int* __restrict__ rank, const int* __restrict__ row_start,
                               const int* __restrict__ pref, int2* __restrict__ csr,
                               const float* __restrict__ dinv, int e) {
    int gid = blockIdx.x * 256 + threadIdx.x;
    int i0 = gid * 4;
    if (i0 >= e) return;
    int4 dv = *(const int4*)&dst[i0];
    int4 sv = *(const int4*)&src[i0];
    int4 rv = *(const int4*)&rank[i0];
    int d[4] = {dv.x, dv.y, dv.z, dv.w};
    int s[4] = {sv.x, sv.y, sv.z, sv.w};
    int r[4] = {rv.x, rv.y, rv.z, rv.w};
    int pos[4];
    float w[4];
    #pragma unroll
    for (int q = 0; q < 4; ++q) {
        int rep = REP_OF(i0 + q);
        pos[q] = row_start[d[q]] + pref[rep * N_NODES + d[q]] + r[q];
        w[q] = dinv[d[q]] * dinv[s[q]];
    }
    #pragma unroll
    for (int q = 0; q < 4; ++q)
        csr[pos[q]] = make_int2(s[q], __float_as_int(w[q]));
}

// x0 -> packed bf16 x; h = alpha * x0 (exact f32).
__global__ void init_kernel(const float2* __restrict__ x0, unsigned int* __restrict__ xb,
                            float2* __restrict__ h, int n2) {
    int i = blockIdx.x * blockDim.x + threadIdx.x;
    if (i < n2) {
        float2 v = x0[i];
        xb[i] = pack_bf2(v.x, v.y);
        h[i] = make_float2(ALPHA * v.x, ALPHA * v.y);
    }
}

// 32-bit offsets: xb spans 50000*64 dwords (12.8MB) -> fits a 32-bit voffset;
// avoids per-gather 64-bit address arithmetic.
#define GATHER_BLOCK(W)                                                         \
    {                                                                           \
        unsigned int g[W];                                                      \
        float wv[W];                                                            \
        _Pragma("unroll") for (int q = 0; q < W; ++q) {                         \
            int s = __shfl(rec.x, j + q);                                       \
            wv[q] = __int_as_float(__shfl(rec.y, j + q));                       \
            g[q] = xb[(unsigned int)s * 64u + (unsigned int)lane];              \
        }                                                                       \
        _Pragma("unroll") for (int q = 0; q < W; ++q) {                         \
            accx += wv[q] * bf_lo(g[q]);                                        \
            accy += wv[q] * bf_hi(g[q]);                                        \
        }                                                                       \
        j += W;                                                                 \
    }

// One wave (64 lanes) per node; lane owns features [2*lane, 2*lane+1] (one packed
// dword). Edge records loaded 64-at-a-time coalesced (nontemporal: streamed once,
// don't evict xb from L2), broadcast with shfl; stepped unroll 16/8/4.
// yb written nontemporal; h RMW (every 2nd hop) nontemporal both ways.
// update_h: h += c*(x_k + x_{k+1}) using the rounded self-row (x_k) + fresh acc.
__global__ __launch_bounds__(256) void agg_kernel(
    const unsigned int* __restrict__ xb, unsigned int* __restrict__ yb,
    float2* __restrict__ h2, const float* __restrict__ selfw,
    const int* __restrict__ row_start, const int2* __restrict__ csr, int update_h) {
    int wid = threadIdx.x >> 6;
    int lane = threadIdx.x & 63;
    int node = blockIdx.x * 4 + wid;
    if (node >= N_NODES) return;

    int r0 = row_start[node];
    int r1 = row_start[node + 1];
    int deg = r1 - r0;
    unsigned int o = (unsigned int)node * 64u + (unsigned int)lane;

    unsigned int vw = xb[o];
    float sw = selfw[node];
    float accx = sw * bf_lo(vw), accy = sw * bf_hi(vw);

    for (int base = 0; base < deg; base += 64) {
        int cnt = deg - base;
        if (cnt > 64) cnt = 64;
        int idx = r0 + base + lane;
        if (idx >= r1) idx = r1 - 1;           // clamped lanes are never shfl-read
        long long rr = __builtin_nontemporal_load((const long long*)&csr[idx]);
        int2 rec;
        rec.x = (int)rr;                       // src
        rec.y = (int)(rr >> 32);               // bitcast(weight)

        int j = 0;
        while (j + 16 <= cnt) GATHER_BLOCK(16);
        if (j + 8 <= cnt) GATHER_BLOCK(8);
        if (j + 4 <= cnt) GATHER_BLOCK(4);
        for (; j < cnt; ++j) {
            int s = __shfl(rec.x, j);
            float w = __int_as_float(__shfl(rec.y, j));
            unsigned int gw = xb[(unsigned int)s * 64u + (unsigned int)lane];
            accx += w * bf_lo(gw);
            accy += w * bf_hi(gw);
        }
    }

    __builtin_nontemporal_store(pack_bf2(accx, accy), &yb[o]);   // bf16 next-hop state
    if (update_h) {
        union { long long ll; float2 f; } hu;
        hu.ll = __builtin_nontemporal_load((const long long*)&h2[o]);
        hu.f.x += HCOEF * (bf_lo(vw) + accx);  // x_k (rounded) + x_{k+1} (pre-round)
        hu.f.y += HCOEF * (bf_hi(vw) + accy);
        __builtin_nontemporal_store(hu.ll, (long long*)&h2[o]);
    }
}

// out[r][c] = sum_k h[r][k]*W[c][k] + bias[c]. h and out are DIFFERENT buffers.
// Block: 64 rows x 64 cols, 256 threads, 4x4 acc/thread. k-major LDS tiles.
__global__ __launch_bounds__(256) void gemm_kernel(
    const float* __restrict__ h, const float* __restrict__ w,
    const float* __restrict__ bias, float* __restrict__ out) {
    __shared__ float sAT[128][64];   // [k][row]
    __shared__ float sBT[128][64];   // [k][col]
    int tid = threadIdx.x;
    int row0 = blockIdx.x * 64;
    int col0 = blockIdx.y * 64;

    for (int idx = tid; idx < 64 * 32; idx += 256) {
        int r = idx & 63, kq = idx >> 6;
        float4 v;
        if (row0 + r < N_NODES)
            v = *(const float4*)&h[(size_t)(row0 + r) * D + kq * 4];
        else
            v = make_float4(0.f, 0.f, 0.f, 0.f);
        sAT[kq * 4 + 0][r] = v.x;
        sAT[kq * 4 + 1][r] = v.y;
        sAT[kq * 4 + 2][r] = v.z;
        sAT[kq * 4 + 3][r] = v.w;
    }
    for (int idx = tid; idx < 64 * 32; idx += 256) {
        int c = idx & 63, kq = idx >> 6;
        float4 v = *(const float4*)&w[(size_t)(col0 + c) * D + kq * 4];
        sBT[kq * 4 + 0][c] = v.x;
        sBT[kq * 4 + 1][c] = v.y;
        sBT[kq * 4 + 2][c] = v.z;
        sBT[kq * 4 + 3][c] = v.w;
    }
    __syncthreads();

    int cg = tid & 15;    // cols cg*4..+4
    int rg = tid >> 4;    // rows rg*4..+4
    float acc[4][4] = {};
    #pragma unroll 2
    for (int k = 0; k < 128; ++k) {
        float4 a = *(const float4*)&sAT[k][rg * 4];
        float4 b = *(const float4*)&sBT[k][cg * 4];
        acc[0][0] += a.x * b.x; acc[0][1] += a.x * b.y; acc[0][2] += a.x * b.z; acc[0][3] += a.x * b.w;
        acc[1][0] += a.y * b.x; acc[1][1] += a.y * b.y; acc[1][2] += a.y * b.z; acc[1][3] += a.y * b.w;
        acc[2][0] += a.z * b.x; acc[2][1] += a.z * b.y; acc[2][2] += a.z * b.z; acc[2][3] += a.z * b.w;
        acc[3][0] += a.w * b.x; acc[3][1] += a.w * b.y; acc[3][2] += a.w * b.z; acc[3][3] += a.w * b.w;
    }

    float4 bv = *(const float4*)&bias[col0 + cg * 4];
    #pragma unroll
    for (int i = 0; i < 4; ++i) {
        int r = row0 + rg * 4 + i;
        if (r < N_NODES) {
            float4 ov = make_float4(acc[i][0] + bv.x, acc[i][1] + bv.y,
                                    acc[i][2] + bv.z, acc[i][3] + bv.w);
            *(float4*)&out[(size_t)r * D + col0 + cg * 4] = ov;
        }
    }
}

extern "C" void kernel_launch(void* const* d_in, const int* in_sizes, int n_in,
                              void* d_out, int out_size, void* d_ws, size_t ws_size,
                              hipStream_t stream) {
    const float* node_emb = (const float*)d_in[0];
    const int*   edge     = (const int*)d_in[1];   // [2,E]: row 0 = src, row 1 = dst
    const float* weight   = (const float*)d_in[2]; // [D_OUT, D_IN] row-major
    const float* bias     = (const float*)d_in[3];
    float* out = (float*)d_out;

    char* ws = (char*)d_ws;
    float*        hbuf = (float*)ws;        ws += (size_t)N_NODES * D * sizeof(float);
    unsigned int* xb0  = (unsigned int*)ws; ws += (size_t)N_NODES * 64 * sizeof(unsigned int);
    unsigned int* xb1  = (unsigned int*)ws; ws += (size_t)N_NODES * 64 * sizeof(unsigned int);
    int2*  csr      = (int2*)ws;  ws += (size_t)N_EDGES * sizeof(int2);
    int*   rank     = (int*)ws;   ws += (size_t)N_EDGES * sizeof(int);
    int*   degR     = (int*)ws;   ws += (size_t)NREP * N_NODES * sizeof(int);  // -> pref
    int*   deg      = (int*)ws;   ws += (size_t)N_NODES * sizeof(int);
    int*   row_start= (int*)ws;   ws += (size_t)(N_NODES + 16) * sizeof(int);
    float* dinv     = (float*)ws; ws += (size_t)N_NODES * sizeof(float);
    float* selfw    = (float*)ws; ws += (size_t)N_NODES * sizeof(float);
    int*   part     = (int*)ws;   ws += 256 * sizeof(int);

    const int* srcp = edge;
    const int* dstp = edge + N_EDGES;

    hipMemsetAsync(degR, 0, (size_t)NREP * N_NODES * sizeof(int), stream);

    int deg_threads = N_EDGES / DEG_IPT;                       // 200000, exact
    deg_kernel<<<(deg_threads + 255) / 256, 256, 0, stream>>>(dstp, degR, rank, N_EDGES);
    combine_kernel<<<(N_NODES + 255) / 256, 256, 0, stream>>>(degR, deg, dinv, selfw, N_NODES);
    scan_part<<<N_SBLK, 256, 0, stream>>>(deg, part, N_NODES);
    scan_mid<<<1, 256, 0, stream>>>(part, N_SBLK);
    scan_fin<<<N_SBLK, 256, 0, stream>>>(deg, part, row_start, N_NODES);
    int sc_threads = N_EDGES / 4;                              // 400000, exact
    scatter_kernel<<<(sc_threads + 255) / 256, 256, 0, stream>>>(srcp, dstp, rank, row_start,
                                                                 degR, csr, dinv, N_EDGES);

    int n2 = N_NODES * D / 2;
    init_kernel<<<(n2 + 255) / 256, 256, 0, stream>>>((const float2*)node_emb, xb0,
                                                      (float2*)hbuf, n2);

    unsigned int* cur = xb0;
    unsigned int* nxt = xb1;
    for (int k = 0; k < K_HOPS; ++k) {
        agg_kernel<<<(N_NODES + 3) / 4, 256, 0, stream>>>(cur, nxt, (float2*)hbuf,
                                                          selfw, row_start, csr, k & 1);
        unsigned int* tmp = cur; cur = nxt; nxt = tmp;
    }

    // Out-of-place GEMM: reads hbuf (f32), writes d_out.
    dim3 ggrid((N_NODES + 63) / 64, 2);
    gemm_kernel<<<ggrid, 256, 0, stream>>>(hbuf, weight, bias, out);
}